// Round 1
// baseline (226.591 us; speedup 1.0000x reference)
//
#include <hip/hip_runtime.h>
#include <math.h>

#define BB 8
#define NN 512
#define DD 512
#define DKK 64
#define NC 192                  // 3*DK
#define CHN (BB * DKK * NN)     // floats per Q (or K or V) image
#define SAEL (BB * NN * DKK)    // 262144 SA elements
#define WEL (NC * DD)           // 98304 elements in W_qkv
#define WOEL (DKK * DD)         // 32768 elements in W_o
#define NFRAG_W (WEL / 8)       // 12288 W fragments
#define NFRAG_WO (WOEL / 8)     // 4096 Wo fragments
#define NJ 20                   // Taylor terms
#define NBLK 256                // grid size (power of 2, == #CUs)

typedef short s8v   __attribute__((ext_vector_type(8)));
typedef float f32x4 __attribute__((ext_vector_type(4)));
typedef unsigned short ushort;

// exact-ish split: w ~= hi + lo, hi = trunc16(w), lo = trunc16(w - hi).
static __device__ __forceinline__ void split2(float w, ushort& h, ushort& l) {
    const unsigned u = __float_as_uint(w);
    h = (ushort)(u >> 16);
    const float lo = w - __uint_as_float(u & 0xFFFF0000u);
    l = (ushort)(__float_as_uint(lo) >> 16);
}

// 1/j! for j=0..19
__constant__ float c_invfact[NJ] = {
    1.0f, 1.0f, 0.5f, 1.6666667e-1f, 4.1666668e-2f, 8.3333338e-3f,
    1.3888889e-3f, 1.9841270e-4f, 2.4801588e-5f, 2.7557319e-6f,
    2.7557319e-7f, 2.5052108e-8f, 2.0876757e-9f, 1.6059044e-10f,
    1.1470746e-11f, 7.6471637e-13f, 4.7794773e-14f, 2.8114572e-15f,
    1.5619207e-16f, 8.2206352e-18f};

// ---------------------------------------------------------------------------
// Device-wide barrier. Monotonic arrive counter in a __device__ global (NOT
// workspace -> immune to harness poison-fill; survives graph replays since
// round = v/NBLK arithmetic only needs monotonicity; wrap-safe compare).
// Release side: __syncthreads drains each wave's vmcnt -> all block stores in
// this XCD's L2; thread0's __threadfence (agent acq_rel) writes back L2.
// Acquire side: agent-acquire fence invalidates L1/L2 so post-barrier reads
// can't hit stale (poison-filled) lines. This replicates the implicit fences
// at kernel boundaries of the previous 4-dispatch version.
// ---------------------------------------------------------------------------
__device__ unsigned g_bar = 0;

static __device__ __forceinline__ void gridbar(int tid) {
    __syncthreads();
    if (tid == 0) {
        __threadfence();   // release: wbl2, make block's stores device-visible
        const unsigned v = __hip_atomic_fetch_add(&g_bar, 1u, __ATOMIC_ACQ_REL,
                                                  __HIP_MEMORY_SCOPE_AGENT);
        const unsigned target = (v & ~(unsigned)(NBLK - 1)) + NBLK;
        unsigned cur = v + 1;
        int guard = 0;
        while ((int)(cur - target) < 0 && guard < (1 << 24)) {  // bailout: hang->fail
            __builtin_amdgcn_s_sleep(1);
            cur = __hip_atomic_load(&g_bar, __ATOMIC_RELAXED,
                                    __HIP_MEMORY_SCOPE_AGENT);
            ++guard;
        }
    }
    __syncthreads();
    __builtin_amdgcn_fence(__ATOMIC_ACQUIRE, "agent");  // invalidate L1/L2
}

// ---------------------------------------------------------------------------
// ONE cooperative kernel, 256 blocks x 768 threads (12 waves), 1 block/CU.
//   P0: stage X seq-tile into LDS A-frags  +  64 W-frag jobs (wave 11)
//   P1: QKV MFMA (wave = ct tile)                       [gridbar]
//   P2: Taylor-moment attention, 2 channels/block       [gridbar]
//   P3: out = SA @ Wo MFMA (waves 0-7)                  [gridbar]
// LDS: A-frags (33.3 KB) unioned with attention part/red/coef (85.6 KB).
// 85.6 KB LDS also structurally forces 1 block/CU.
// ---------------------------------------------------------------------------
__global__ __launch_bounds__(768) void fused(
    const float* __restrict__ X, const float* __restrict__ W,
    const float* __restrict__ Wo,
    ushort* __restrict__ Wfh, ushort* __restrict__ Wfl,
    ushort* __restrict__ Woh, ushort* __restrict__ Wol,
    float* __restrict__ qkv,
    ushort* __restrict__ SAh, ushort* __restrict__ SAl,
    float* __restrict__ out) {

    __shared__ union {
        struct { ushort Ah[16 * 512 + 128]; ushort Al[16 * 512 + 128]; } q;
        struct {
            float part[2][256][41];
            float red[2][2 * NJ][4];
            float coef[2][2 * NJ];
        } a;
    } sm;

    const int tid = threadIdx.x;
    const int st  = blockIdx.x;            // 0..255 seq-tile

    // ================= P0: X staging + W fragment prep =================
    for (int i = tid; i < 2048; i += 768) {
        const int row = i >> 7;             // 0..15
        const int k0  = (i & 127) * 4;      // 0..508 step 4
        const float4 x = *(const float4*)(X + (size_t)(st * 16 + row) * DD + k0);
        const float xe[4] = {x.x, x.y, x.z, x.w};
        ushort h[4], l[4];
        #pragma unroll
        for (int e = 0; e < 4; ++e) split2(xe[e], h[e], l[e]);
        const int ks   = k0 >> 5;
        const int quad = (k0 >> 3) & 3;
        const int e0   = k0 & 7;
        const int lane = quad * 16 + row;
        const size_t a = (size_t)(ks * 64 + lane) * 8 + e0 + ks * 8;
        *(ushort4*)(sm.q.Ah + a) = make_ushort4(h[0], h[1], h[2], h[3]);
        *(ushort4*)(sm.q.Al + a) = make_ushort4(l[0], l[1], l[2], l[3]);
    }
    // 16384 W-frag jobs spread 64/block on wave 11 (lightest staging load);
    // consecutive lanes -> consecutive 16B frag stores (coalesced).
    if (tid >= 704) {
        const int gtid = st * 64 + (tid - 704);
        if (gtid < NFRAG_W) {
            const int ct   = gtid >> 10;
            const int ks   = (gtid >> 6) & 15;
            const int lane = gtid & 63;
            const int lm   = lane & 15;
            const int quad = lane >> 4;
            const int chan = ct * 16 + lm;
            const int k0   = ks * 32 + quad * 8;
            s8v h, l;
            #pragma unroll
            for (int e = 0; e < 8; ++e) {
                ushort hh, ll;
                split2(W[(size_t)(k0 + e) * NC + chan], hh, ll);
                h[e] = (short)hh;
                l[e] = (short)ll;
            }
            *(s8v*)(Wfh + (size_t)gtid * 8) = h;
            *(s8v*)(Wfl + (size_t)gtid * 8) = l;
        } else {
            const int fi   = gtid - NFRAG_W;
            const int lane = fi & 63;
            const int ks   = (fi >> 6) & 1;
            const int dt   = fi >> 7;
            const int lm   = lane & 15;
            const int quad = lane >> 4;
            const int d    = dt * 16 + lm;
            s8v h, l;
            #pragma unroll
            for (int e = 0; e < 8; ++e) {
                ushort hh, ll;
                split2(Wo[(size_t)(ks * 32 + quad * 8 + e) * DD + d], hh, ll);
                h[e] = (short)hh;
                l[e] = (short)ll;
            }
            *(s8v*)(Woh + (size_t)fi * 8) = h;
            *(s8v*)(Wol + (size_t)fi * 8) = l;
        }
    }
    gridbar(tid);

    // ================= P1: QKV MFMA (wave = one ct tile) =================
    {
        const int ct   = tid >> 6;          // 0..11
        const int lane = tid & 63;
        const int lm   = lane & 15;
        const int quad = lane >> 4;
        const int chan = ct * 16 + lm;      // 0..191

        const ushort* bw_h = Wfh + ((size_t)(ct * 16) * 64 + lane) * 8;
        const ushort* bw_l = Wfl + ((size_t)(ct * 16) * 64 + lane) * 8;

        f32x4 acc = {0.f, 0.f, 0.f, 0.f};
        #pragma unroll 4
        for (int ks = 0; ks < 16; ++ks) {
            const size_t woff = (size_t)ks * 512;
            const s8v bh = *(const s8v*)(bw_h + woff);
            const s8v bl = *(const s8v*)(bw_l + woff);
            const size_t a = (size_t)(ks * 64 + lane) * 8 + ks * 8;
            const s8v ah = *(const s8v*)(sm.q.Ah + a);
            const s8v al = *(const s8v*)(sm.q.Al + a);
            acc = __builtin_amdgcn_mfma_f32_16x16x32_bf16(ah, bh, acc, 0, 0, 0);
            acc = __builtin_amdgcn_mfma_f32_16x16x32_bf16(ah, bl, acc, 0, 0, 0);
            acc = __builtin_amdgcn_mfma_f32_16x16x32_bf16(al, bh, acc, 0, 0, 0);
        }
        const int which = chan >> 6;
        const int c     = chan & 63;
        const int seq0  = st * 16 + quad * 4;
        const int b     = seq0 >> 9;
        const int n0    = seq0 & 511;
        const float4 v = {acc[0], acc[1], acc[2], acc[3]};
        *(float4*)(qkv + (size_t)which * CHN + ((size_t)(b * DKK + c)) * NN + n0) = v;
    }
    gridbar(tid);

    // ================= P2: Taylor attention, 2 channels/block =============
    const int h2 = tid >> 8;               // 0,1 (2 = idle waves 8-11)
    const int t2 = tid & 255;
    if (tid < 512) {
        const int cidx  = st * 2 + h2;     // 0..511
        const float* kp = qkv + CHN + (size_t)cidx * NN;
        const float* vp = qkv + 2 * CHN + (size_t)cidx * NN;
        const float k0 = kp[t2], k1 = kp[t2 + 256];
        const float v0 = vp[t2], v1 = vp[t2 + 256];
        float p0 = 1.f, p1 = 1.f;
        #pragma unroll
        for (int j = 0; j < NJ; ++j) {
            sm.a.part[h2][t2][j]      = fmaf(p0, v0, p1 * v1);  // mu_j partial
            sm.a.part[h2][t2][NJ + j] = p0 + p1;                // nu_j partial
            p0 *= k0;
            p1 *= k1;
        }
    }
    __syncthreads();
    // parallel column reduction: 160 threads/channel, 64 rows each
    // (was: 40 threads x 256 serial reads)
    if (tid < 512 && t2 < 160) {
        const int j = t2 >> 2, g = t2 & 3;
        float s = 0.f;
        #pragma unroll 8
        for (int i = 0; i < 64; ++i) s += sm.a.part[h2][i * 4 + g][j];
        sm.a.red[h2][j][g] = s;
    }
    __syncthreads();
    if (tid < 512 && t2 < 2 * NJ) {
        const int jj = (t2 < NJ) ? t2 : t2 - NJ;
        sm.a.coef[h2][t2] = (sm.a.red[h2][t2][0] + sm.a.red[h2][t2][1] +
                             sm.a.red[h2][t2][2] + sm.a.red[h2][t2][3]) *
                            c_invfact[jj];
    }
    __syncthreads();
    if (tid < 512) {
        const int cidx  = st * 2 + h2;
        const float* qp = qkv + (size_t)cidx * NN;
        float c[2 * NJ];
        #pragma unroll
        for (int j = 0; j < 2 * NJ; ++j) c[j] = sm.a.coef[h2][j];

        const int b   = cidx >> 6;
        const int ch  = cidx & 63;
        const int ks  = ch >> 5;
        const int jf  = ch & 7;
        const int lhi = ((ch & 31) >> 3) << 4;

        #pragma unroll
        for (int r = 0; r < 2; ++r) {
            const int n   = t2 + r * 256;
            const float t = qp[n] * 0.125f;  // 1/sqrt(64)
            float P = c[NJ - 1];
            float Q = c[2 * NJ - 1];
            #pragma unroll
            for (int j = NJ - 2; j >= 0; --j) {
                P = fmaf(P, t, c[j]);
                Q = fmaf(Q, t, c[NJ + j]);
            }
            const float val = P / Q;
            ushort hi, lo;
            split2(val, hi, lo);
            const int gseq  = b * NN + n;
            const int stg   = gseq >> 4;
            const int lane  = lhi | (gseq & 15);
            const size_t addr = ((size_t)(stg * 2 + ks) * 64 + lane) * 8 + jf;
            SAh[addr] = hi;
            SAl[addr] = lo;
        }
    }
    gridbar(tid);

    // ================= P3: out = SA @ Wo (waves 0-7) =====================
    const int w3 = tid >> 6;
    if (w3 < 8) {
        const int lane = tid & 63;
        const int lm   = lane & 15;
        const int quad = lane >> 4;
        const int dg   = w3;               // 64-d group

        const ushort* sa_h = SAh + ((size_t)(st * 2) * 64 + lane) * 8;
        const ushort* sa_l = SAl + ((size_t)(st * 2) * 64 + lane) * 8;
        const s8v ah0 = *(const s8v*)(sa_h);
        const s8v ah1 = *(const s8v*)(sa_h + 512);
        const s8v al0 = *(const s8v*)(sa_l);
        const s8v al1 = *(const s8v*)(sa_l + 512);

        const int seq0 = st * 16 + quad * 4;

        #pragma unroll
        for (int dti = 0; dti < 4; ++dti) {
            const int dt = dg * 4 + dti;
            const int d  = dt * 16 + lm;

            const ushort* wo_h = Woh + ((size_t)(dt * 2) * 64 + lane) * 8;
            const ushort* wo_l = Wol + ((size_t)(dt * 2) * 64 + lane) * 8;
            const s8v bh0 = *(const s8v*)(wo_h);
            const s8v bh1 = *(const s8v*)(wo_h + 512);
            const s8v bl0 = *(const s8v*)(wo_l);
            const s8v bl1 = *(const s8v*)(wo_l + 512);

            f32x4 acc = {0.f, 0.f, 0.f, 0.f};
            acc = __builtin_amdgcn_mfma_f32_16x16x32_bf16(ah0, bh0, acc, 0, 0, 0);
            acc = __builtin_amdgcn_mfma_f32_16x16x32_bf16(ah0, bl0, acc, 0, 0, 0);
            acc = __builtin_amdgcn_mfma_f32_16x16x32_bf16(al0, bh0, acc, 0, 0, 0);
            acc = __builtin_amdgcn_mfma_f32_16x16x32_bf16(ah1, bh1, acc, 0, 0, 0);
            acc = __builtin_amdgcn_mfma_f32_16x16x32_bf16(ah1, bl1, acc, 0, 0, 0);
            acc = __builtin_amdgcn_mfma_f32_16x16x32_bf16(al1, bh1, acc, 0, 0, 0);

            #pragma unroll
            for (int r = 0; r < 4; ++r)
                out[(size_t)(seq0 + r) * DD + d] = acc[r];
        }
    }
}

extern "C" void kernel_launch(void* const* d_in, const int* in_sizes, int n_in,
                              void* d_out, int out_size, void* d_ws, size_t ws_size,
                              hipStream_t stream) {
    const float* X    = (const float*)d_in[0];  // (8,512,512)
    const float* Wqkv = (const float*)d_in[1];  // (512,192)
    const float* Wo   = (const float*)d_in[2];  // (64,512)
    float* out = (float*)d_out;                 // (8,512,512)

    float*  qkv = (float*)d_ws;                         // 3 MB
    ushort* SAh = (ushort*)(qkv + (size_t)3 * CHN);     // 512 KB
    ushort* SAl = SAh + (size_t)SAEL;                   // 512 KB
    ushort* Wfh = SAl + (size_t)SAEL;                   // 192 KB
    ushort* Wfl = Wfh + (size_t)WEL;                    // 192 KB
    ushort* Woh = Wfl + (size_t)WEL;                    // 64 KB
    ushort* Wol = Woh + (size_t)WOEL;                   // 64 KB

    void* args[] = {(void*)&X,   (void*)&Wqkv, (void*)&Wo,
                    (void*)&Wfh, (void*)&Wfl,  (void*)&Woh, (void*)&Wol,
                    (void*)&qkv, (void*)&SAh,  (void*)&SAl, (void*)&out};
    hipLaunchCooperativeKernel((void*)fused, dim3(NBLK), dim3(768), args, 0,
                               stream);
}

// Round 2
// 79.786 us; speedup vs baseline: 2.8400x; 2.8400x over previous
//
#include <hip/hip_runtime.h>
#include <math.h>

#define BB 8
#define NN 512
#define DD 512
#define DKK 64
#define NC 192                  // 3*DK
#define CHN (BB * DKK * NN)     // floats per Q (or K or V) image
#define SAEL (BB * NN * DKK)    // 262144 SA elements
#define WEL (NC * DD)           // 98304 elements in W_qkv
#define WOEL (DKK * DD)         // 32768 elements in W_o
#define NFRAG_W (WEL / 8)       // 12288 W fragments
#define NFRAG_WO (WOEL / 8)     // 4096 Wo fragments
#define NJ 20                   // Taylor terms

typedef short s8v   __attribute__((ext_vector_type(8)));
typedef float f32x4 __attribute__((ext_vector_type(4)));
typedef unsigned short ushort;

// exact-ish split: w ~= hi + lo, hi = trunc16(w), lo = trunc16(w - hi).
static __device__ __forceinline__ void split2(float w, ushort& h, ushort& l) {
    const unsigned u = __float_as_uint(w);
    h = (ushort)(u >> 16);
    const float lo = w - __uint_as_float(u & 0xFFFF0000u);
    l = (ushort)(__float_as_uint(lo) >> 16);
}

// 1/j! for j=0..19
__constant__ float c_invfact[NJ] = {
    1.0f, 1.0f, 0.5f, 1.6666667e-1f, 4.1666668e-2f, 8.3333338e-3f,
    1.3888889e-3f, 1.9841270e-4f, 2.4801588e-5f, 2.7557319e-6f,
    2.7557319e-7f, 2.5052108e-8f, 2.0876757e-9f, 1.6059044e-10f,
    1.1470746e-11f, 7.6471637e-13f, 4.7794773e-14f, 2.8114572e-15f,
    1.5619207e-16f, 8.2206352e-18f};

// -------------------------------------------------------------------------
// Kernel 0 (wprep): weight fragments, computed ONCE. 512 KB total,
// L2-resident.  (unchanged from the 80 us baseline)
// -------------------------------------------------------------------------
__global__ __launch_bounds__(256) void wprep(const float* __restrict__ W,
                                             const float* __restrict__ Wo,
                                             ushort* __restrict__ Wfh,
                                             ushort* __restrict__ Wfl,
                                             ushort* __restrict__ Woh,
                                             ushort* __restrict__ Wol) {
    const int gtid = blockIdx.x * 256 + threadIdx.x;
    if (gtid < NFRAG_W) {
        const int ct   = gtid >> 10;
        const int ks   = (gtid >> 6) & 15;
        const int lane = gtid & 63;
        const int lm   = lane & 15;
        const int quad = lane >> 4;
        const int chan = ct * 16 + lm;
        const int k0   = ks * 32 + quad * 8;
        s8v h, l;
        #pragma unroll
        for (int e = 0; e < 8; ++e) {
            ushort hh, ll;
            split2(W[(size_t)(k0 + e) * NC + chan], hh, ll);
            h[e] = (short)hh;
            l[e] = (short)ll;
        }
        *(s8v*)(Wfh + (size_t)gtid * 8) = h;
        *(s8v*)(Wfl + (size_t)gtid * 8) = l;
        return;
    }
    const int fi = gtid - NFRAG_W;
    if (fi < NFRAG_WO) {
        const int lane = fi & 63;
        const int ks   = (fi >> 6) & 1;
        const int dt   = fi >> 7;
        const int lm   = lane & 15;
        const int quad = lane >> 4;
        const int d    = dt * 16 + lm;
        s8v h, l;
        #pragma unroll
        for (int e = 0; e < 8; ++e) {
            ushort hh, ll;
            split2(Wo[(size_t)(ks * 32 + quad * 8 + e) * DD + d], hh, ll);
            h[e] = (short)hh;
            l[e] = (short)ll;
        }
        *(s8v*)(Woh + (size_t)fi * 8) = h;
        *(s8v*)(Wol + (size_t)fi * 8) = l;
    }
}

// -------------------------------------------------------------------------
// Kernel 1: FUSED X-prep + QKV MFMA, one block (12 waves) per seq-tile st.
// CHANGE vs 80us baseline: ALL 32 W-fragment b128 loads are issued into
// registers BEFORE the X-staging phase (32-deep MLP, latency hidden under
// staging HBM loads), and the MFMA loop is fully unrolled reading regs+LDS.
// Previously: 8-deep MLP inside the loop -> ~20 us latency-bound L2 stream.
// -------------------------------------------------------------------------
__global__ __launch_bounds__(768) void qkv_fused(const float* __restrict__ X,
                                                 const ushort* __restrict__ Wfh,
                                                 const ushort* __restrict__ Wfl,
                                                 float* __restrict__ qkv) {
    __shared__ ushort Ah[16 * 512 + 128];  // frag layout + ks*8 ushort skew
    __shared__ ushort Al[16 * 512 + 128];

    const int st  = blockIdx.x;            // 0..255
    const int tid = threadIdx.x;
    const int ct   = tid >> 6;              // 0..11
    const int lane = tid & 63;
    const int lm   = lane & 15;
    const int quad = lane >> 4;

    // ---- issue all W-fragment loads first (in flight during staging) ----
    const ushort* bw_h = Wfh + ((size_t)(ct * 16) * 64 + lane) * 8;
    const ushort* bw_l = Wfl + ((size_t)(ct * 16) * 64 + lane) * 8;
    s8v bh[16], bl[16];
    #pragma unroll
    for (int ks = 0; ks < 16; ++ks) {
        bh[ks] = *(const s8v*)(bw_h + (size_t)ks * 512);
        bl[ks] = *(const s8v*)(bw_l + (size_t)ks * 512);
    }

    // ---- stage & convert X st-tile into skewed A-fragment layout ----
    for (int i = tid; i < 2048; i += 768) {
        const int row = i >> 7;             // 0..15
        const int k0  = (i & 127) * 4;      // 0..508 step 4
        const float4 x = *(const float4*)(X + (size_t)(st * 16 + row) * DD + k0);
        const float xe[4] = {x.x, x.y, x.z, x.w};
        ushort h[4], l[4];
        #pragma unroll
        for (int e = 0; e < 4; ++e) split2(xe[e], h[e], l[e]);
        const int ks   = k0 >> 5;
        const int qd   = (k0 >> 3) & 3;
        const int e0   = k0 & 7;            // 0 or 4
        const int ln   = qd * 16 + row;
        const size_t a = (size_t)(ks * 64 + ln) * 8 + e0 + ks * 8;
        *(ushort4*)(Ah + a) = make_ushort4(h[0], h[1], h[2], h[3]);
        *(ushort4*)(Al + a) = make_ushort4(l[0], l[1], l[2], l[3]);
    }
    __syncthreads();

    // ---- MFMA loop: wave = one ct tile; frags already in registers ----
    const int chan = ct * 16 + lm;          // 0..191
    f32x4 acc = {0.f, 0.f, 0.f, 0.f};
    #pragma unroll
    for (int ks = 0; ks < 16; ++ks) {
        const size_t a = (size_t)(ks * 64 + lane) * 8 + ks * 8;  // 16B-aligned
        const s8v ah = *(const s8v*)(Ah + a);
        const s8v al = *(const s8v*)(Al + a);
        acc = __builtin_amdgcn_mfma_f32_16x16x32_bf16(ah, bh[ks], acc, 0, 0, 0);
        acc = __builtin_amdgcn_mfma_f32_16x16x32_bf16(ah, bl[ks], acc, 0, 0, 0);
        acc = __builtin_amdgcn_mfma_f32_16x16x32_bf16(al, bh[ks], acc, 0, 0, 0);
    }

    // C/D: col(chan)=lane&15, row(seq)=quad*4+r -> channel-major float4
    const int which = chan >> 6;
    const int c     = chan & 63;
    const int seq0  = st * 16 + quad * 4;
    const int b     = seq0 >> 9;
    const int n0    = seq0 & 511;
    const float4 v = {acc[0], acc[1], acc[2], acc[3]};
    *(float4*)(qkv + (size_t)which * CHN + ((size_t)(b * DKK + c)) * NN + n0) = v;
}

// -------------------------------------------------------------------------
// Kernel 2: Taylor-moment rank-1 softmax attention.
// CHANGE vs 80us baseline: the column reduction is 160 threads x 64 rows
// (was 40 threads x 256 serial LDS reads).
// -------------------------------------------------------------------------
__global__ __launch_bounds__(256) void attn_taylor(const float* __restrict__ qkv,
                                                   ushort* __restrict__ SAh,
                                                   ushort* __restrict__ SAl) {
    __shared__ float part[256][41];
    __shared__ float red[2 * NJ][4];
    __shared__ float coef[2 * NJ];

    const int tid = threadIdx.x;
    const size_t chan = (size_t)blockIdx.x * NN;
    const float* qp = qkv + chan;
    const float* kp = qkv + CHN + chan;
    const float* vp = qkv + 2 * CHN + chan;

    const float k0 = kp[tid], k1 = kp[tid + 256];
    const float v0 = vp[tid], v1 = vp[tid + 256];

    float p0 = 1.f, p1 = 1.f;
    #pragma unroll
    for (int j = 0; j < NJ; ++j) {
        part[tid][j]      = fmaf(p0, v0, p1 * v1);   // mu_j partial
        part[tid][NJ + j] = p0 + p1;                 // nu_j partial
        p0 *= k0;
        p1 *= k1;
    }
    __syncthreads();

    // parallel column reduction: 160 threads, 64 rows each
    if (tid < 160) {
        const int j = tid >> 2, g = tid & 3;
        float s = 0.f;
        #pragma unroll 8
        for (int i = 0; i < 64; ++i) s += part[i * 4 + g][j];
        red[j][g] = s;
    }
    __syncthreads();
    if (tid < 2 * NJ) {
        const int jj = (tid < NJ) ? tid : tid - NJ;
        coef[tid] = (red[tid][0] + red[tid][1] + red[tid][2] + red[tid][3]) *
                    c_invfact[jj];
    }
    __syncthreads();

    float c[2 * NJ];
    #pragma unroll
    for (int j = 0; j < 2 * NJ; ++j) c[j] = coef[j];

    const int b  = blockIdx.x >> 6;
    const int ch = blockIdx.x & 63;
    const int ks = ch >> 5;
    const int jf = ch & 7;
    const int lhi = ((ch & 31) >> 3) << 4;

    #pragma unroll
    for (int r = 0; r < 2; ++r) {
        const int n = tid + r * 256;
        const float t = qp[n] * 0.125f;  // 1/sqrt(64)
        float P = c[NJ - 1];
        float Q = c[2 * NJ - 1];
        #pragma unroll
        for (int j = NJ - 2; j >= 0; --j) {
            P = fmaf(P, t, c[j]);
            Q = fmaf(Q, t, c[NJ + j]);
        }
        const float val = P / Q;
        ushort hi, lo;
        split2(val, hi, lo);
        const int gseq = b * NN + n;
        const int stg  = gseq >> 4;
        const int lane = lhi | (gseq & 15);
        const size_t addr = ((size_t)(stg * 2 + ks) * 64 + lane) * 8 + jf;
        SAh[addr] = hi;
        SAl[addr] = lo;
    }
}

// -------------------------------------------------------------------------
// Kernel 3: out = SA(4096x64) @ Wo(64x512) on the MFMA pipe.
// CHANGE vs 80us baseline: all 16 Wo-fragment b128 loads hoisted ahead of
// the MFMA chain (16-deep MLP; latency hidden under SA loads).
// -------------------------------------------------------------------------
__global__ __launch_bounds__(256) void out_mfma(const ushort* __restrict__ SAh,
                                                const ushort* __restrict__ SAl,
                                                const ushort* __restrict__ Woh,
                                                const ushort* __restrict__ Wol,
                                                float* __restrict__ out) {
    const int widx = blockIdx.x * 4 + (threadIdx.x >> 6);  // 0..2047
    const int st   = widx >> 3;        // 0..255
    const int dg   = widx & 7;         // 64-d group
    const int lane = threadIdx.x & 63;
    const int lm   = lane & 15;
    const int quad = lane >> 4;

    // hoist all Wo fragments (independent of SA)
    s8v wh0[4], wh1[4], wl0[4], wl1[4];
    #pragma unroll
    for (int dti = 0; dti < 4; ++dti) {
        const int dt = dg * 4 + dti;
        const ushort* wo_h = Woh + ((size_t)(dt * 2) * 64 + lane) * 8;
        const ushort* wo_l = Wol + ((size_t)(dt * 2) * 64 + lane) * 8;
        wh0[dti] = *(const s8v*)(wo_h);
        wh1[dti] = *(const s8v*)(wo_h + 512);
        wl0[dti] = *(const s8v*)(wo_l);
        wl1[dti] = *(const s8v*)(wo_l + 512);
    }

    const ushort* sa_h = SAh + ((size_t)(st * 2) * 64 + lane) * 8;
    const ushort* sa_l = SAl + ((size_t)(st * 2) * 64 + lane) * 8;
    const s8v ah0 = *(const s8v*)(sa_h);
    const s8v ah1 = *(const s8v*)(sa_h + 512);
    const s8v al0 = *(const s8v*)(sa_l);
    const s8v al1 = *(const s8v*)(sa_l + 512);

    const int seq0 = st * 16 + quad * 4;

    #pragma unroll
    for (int dti = 0; dti < 4; ++dti) {
        const int dt = dg * 4 + dti;
        const int d  = dt * 16 + lm;

        f32x4 acc = {0.f, 0.f, 0.f, 0.f};
        acc = __builtin_amdgcn_mfma_f32_16x16x32_bf16(ah0, wh0[dti], acc, 0, 0, 0);
        acc = __builtin_amdgcn_mfma_f32_16x16x32_bf16(ah0, wl0[dti], acc, 0, 0, 0);
        acc = __builtin_amdgcn_mfma_f32_16x16x32_bf16(al0, wh0[dti], acc, 0, 0, 0);
        acc = __builtin_amdgcn_mfma_f32_16x16x32_bf16(ah1, wh1[dti], acc, 0, 0, 0);
        acc = __builtin_amdgcn_mfma_f32_16x16x32_bf16(ah1, wl1[dti], acc, 0, 0, 0);
        acc = __builtin_amdgcn_mfma_f32_16x16x32_bf16(al1, wh1[dti], acc, 0, 0, 0);

        #pragma unroll
        for (int r = 0; r < 4; ++r)
            out[(size_t)(seq0 + r) * DD + d] = acc[r];
    }
}

extern "C" void kernel_launch(void* const* d_in, const int* in_sizes, int n_in,
                              void* d_out, int out_size, void* d_ws, size_t ws_size,
                              hipStream_t stream) {
    const float* X    = (const float*)d_in[0];  // (8,512,512)
    const float* Wqkv = (const float*)d_in[1];  // (512,192)
    const float* Wo   = (const float*)d_in[2];  // (64,512)
    float* out = (float*)d_out;                 // (8,512,512)

    float*  qkv = (float*)d_ws;                         // 3 MB
    ushort* SAh = (ushort*)(qkv + (size_t)3 * CHN);     // 512 KB
    ushort* SAl = SAh + (size_t)SAEL;                   // 512 KB
    ushort* Wfh = SAl + (size_t)SAEL;                   // 192 KB
    ushort* Wfl = Wfh + (size_t)WEL;                    // 192 KB
    ushort* Woh = Wfl + (size_t)WEL;                    // 64 KB
    ushort* Wol = Woh + (size_t)WOEL;                   // 64 KB

    wprep<<<dim3((NFRAG_W + NFRAG_WO) / 256), 256, 0, stream>>>(
        Wqkv, Wo, Wfh, Wfl, Woh, Wol);
    qkv_fused<<<dim3(256), 768, 0, stream>>>(X, Wfh, Wfl, qkv);
    attn_taylor<<<dim3(BB * DKK), 256, 0, stream>>>(qkv, SAh, SAl);
    out_mfma<<<dim3(512), 256, 0, stream>>>(SAh, SAl, Woh, Wol, out);
}

// Round 3
// 78.997 us; speedup vs baseline: 2.8684x; 1.0100x over previous
//
#include <hip/hip_runtime.h>
#include <math.h>

#define BB 8
#define NN 512
#define DD 512
#define DKK 64
#define NC 192                  // 3*DK
#define CHN (BB * DKK * NN)     // floats per Q (or K or V) image
#define SAEL (BB * NN * DKK)    // 262144 SA elements
#define WOEL (DKK * DD)         // 32768 elements in W_o
#define NFRAG_WO (WOEL / 8)     // 4096 Wo fragments
#define NJ 20                   // Taylor terms

typedef short s8v   __attribute__((ext_vector_type(8)));
typedef float f32x4 __attribute__((ext_vector_type(4)));
typedef unsigned short ushort;

// exact-ish split: w ~= hi + lo, hi = trunc16(w), lo = trunc16(w - hi).
static __device__ __forceinline__ void split2(float w, ushort& h, ushort& l) {
    const unsigned u = __float_as_uint(w);
    h = (ushort)(u >> 16);
    const float lo = w - __uint_as_float(u & 0xFFFF0000u);
    l = (ushort)(__float_as_uint(lo) >> 16);
}

// 1/j! for j=0..19
__constant__ float c_invfact[NJ] = {
    1.0f, 1.0f, 0.5f, 1.6666667e-1f, 4.1666668e-2f, 8.3333338e-3f,
    1.3888889e-3f, 1.9841270e-4f, 2.4801588e-5f, 2.7557319e-6f,
    2.7557319e-7f, 2.5052108e-8f, 2.0876757e-9f, 1.6059044e-10f,
    1.1470746e-11f, 7.6471637e-13f, 4.7794773e-14f, 2.8114572e-15f,
    1.5619207e-16f, 8.2206352e-18f};

// -------------------------------------------------------------------------
// Kernel 1: FUSED X-prep + QKV MFMA, one block (12 waves) per seq-tile st.
// CHANGE vs R2: wprep dispatch ELIMINATED. Each wave loads its own raw
// W 16-chan strip (same L2 bytes as the frag arrays) and does the split
// in-register (~1.5M extra VALU instrs chip-wide, hidden under idle VALU).
// -------------------------------------------------------------------------
__global__ __launch_bounds__(768) void qkv_fused(const float* __restrict__ X,
                                                 const float* __restrict__ W,
                                                 float* __restrict__ qkv) {
    __shared__ ushort Ah[16 * 512 + 128];  // frag layout + ks*8 ushort skew
    __shared__ ushort Al[16 * 512 + 128];

    const int st  = blockIdx.x;            // 0..255
    const int tid = threadIdx.x;
    const int ct   = tid >> 6;              // 0..11
    const int lane = tid & 63;
    const int lm   = lane & 15;
    const int quad = lane >> 4;
    const int chan = ct * 16 + lm;          // 0..191

    // ---- stage & convert X st-tile into skewed A-fragment layout ----
    for (int i = tid; i < 2048; i += 768) {
        const int row = i >> 7;             // 0..15
        const int k0  = (i & 127) * 4;      // 0..508 step 4
        const float4 x = *(const float4*)(X + (size_t)(st * 16 + row) * DD + k0);
        const float xe[4] = {x.x, x.y, x.z, x.w};
        ushort h[4], l[4];
        #pragma unroll
        for (int e = 0; e < 4; ++e) split2(xe[e], h[e], l[e]);
        const int ks   = k0 >> 5;
        const int qd   = (k0 >> 3) & 3;
        const int e0   = k0 & 7;            // 0 or 4
        const int ln   = qd * 16 + row;
        const size_t a = (size_t)(ks * 64 + ln) * 8 + e0 + ks * 8;
        *(ushort4*)(Ah + a) = make_ushort4(h[0], h[1], h[2], h[3]);
        *(ushort4*)(Al + a) = make_ushort4(l[0], l[1], l[2], l[3]);
    }
    __syncthreads();

    // ---- MFMA loop: wave = one ct tile; B-frags split inline from raw W ----
    const float* wcol = W + chan;           // + row*NC indexes down the column
    f32x4 acc = {0.f, 0.f, 0.f, 0.f};

    #pragma unroll
    for (int ks = 0; ks < 16; ++ks) {
        const int k0 = ks * 32 + quad * 8;
        float raw[8];
        #pragma unroll
        for (int e = 0; e < 8; ++e) raw[e] = wcol[(size_t)(k0 + e) * NC];
        s8v bh, bl;
        #pragma unroll
        for (int e = 0; e < 8; ++e) {
            ushort hh, ll;
            split2(raw[e], hh, ll);
            bh[e] = (short)hh;
            bl[e] = (short)ll;
        }
        const size_t a = (size_t)(ks * 64 + lane) * 8 + ks * 8;  // 16B-aligned
        const s8v ah = *(const s8v*)(Ah + a);
        const s8v al = *(const s8v*)(Al + a);
        acc = __builtin_amdgcn_mfma_f32_16x16x32_bf16(ah, bh, acc, 0, 0, 0);
        acc = __builtin_amdgcn_mfma_f32_16x16x32_bf16(ah, bl, acc, 0, 0, 0);
        acc = __builtin_amdgcn_mfma_f32_16x16x32_bf16(al, bh, acc, 0, 0, 0);
    }

    // C/D: col(chan)=lane&15, row(seq)=quad*4+r -> channel-major float4
    const int which = chan >> 6;
    const int c     = chan & 63;
    const int seq0  = st * 16 + quad * 4;
    const int b     = seq0 >> 9;
    const int n0    = seq0 & 511;
    const float4 v = {acc[0], acc[1], acc[2], acc[3]};
    *(float4*)(qkv + (size_t)which * CHN + ((size_t)(b * DKK + c)) * NN + n0) = v;
}

// -------------------------------------------------------------------------
// Kernel 2: Taylor-moment rank-1 softmax attention.
// CHANGE vs R2: absorbs Wo fragment prep (8 jobs/block in the prologue; the
// scattered Wo cold loads overlap the k/v channel loads). attn -> out
// dispatch boundary provides the ordering for out_mfma's reads.
// -------------------------------------------------------------------------
__global__ __launch_bounds__(256) void attn_taylor(const float* __restrict__ qkv,
                                                   const float* __restrict__ Wo,
                                                   ushort* __restrict__ Woh,
                                                   ushort* __restrict__ Wol,
                                                   ushort* __restrict__ SAh,
                                                   ushort* __restrict__ SAl) {
    __shared__ float part[256][41];
    __shared__ float red[2 * NJ][4];
    __shared__ float coef[2 * NJ];

    const int tid = threadIdx.x;

    // ---- Wo fragment prep: 512 blocks x 8 jobs covers all 4096 frags ----
    if (tid < 8) {
        const int fi   = blockIdx.x * 8 + tid;
        const int lane = fi & 63;
        const int ks   = (fi >> 6) & 1;
        const int dt   = fi >> 7;
        const int lm_  = lane & 15;
        const int qd_  = lane >> 4;
        const int d    = dt * 16 + lm_;
        s8v h, l;
        #pragma unroll
        for (int e = 0; e < 8; ++e) {
            ushort hh, ll;
            split2(Wo[(size_t)(ks * 32 + qd_ * 8 + e) * DD + d], hh, ll);
            h[e] = (short)hh;
            l[e] = (short)ll;
        }
        *(s8v*)(Woh + (size_t)fi * 8) = h;
        *(s8v*)(Wol + (size_t)fi * 8) = l;
    }

    const size_t chan = (size_t)blockIdx.x * NN;
    const float* qp = qkv + chan;
    const float* kp = qkv + CHN + chan;
    const float* vp = qkv + 2 * CHN + chan;

    const float k0 = kp[tid], k1 = kp[tid + 256];
    const float v0 = vp[tid], v1 = vp[tid + 256];

    float p0 = 1.f, p1 = 1.f;
    #pragma unroll
    for (int j = 0; j < NJ; ++j) {
        part[tid][j]      = fmaf(p0, v0, p1 * v1);   // mu_j partial
        part[tid][NJ + j] = p0 + p1;                 // nu_j partial
        p0 *= k0;
        p1 *= k1;
    }
    __syncthreads();

    // parallel column reduction: 160 threads, 64 rows each
    if (tid < 160) {
        const int j = tid >> 2, g = tid & 3;
        float s = 0.f;
        #pragma unroll 8
        for (int i = 0; i < 64; ++i) s += part[i * 4 + g][j];
        red[j][g] = s;
    }
    __syncthreads();
    if (tid < 2 * NJ) {
        const int jj = (tid < NJ) ? tid : tid - NJ;
        coef[tid] = (red[tid][0] + red[tid][1] + red[tid][2] + red[tid][3]) *
                    c_invfact[jj];
    }
    __syncthreads();

    float c[2 * NJ];
    #pragma unroll
    for (int j = 0; j < 2 * NJ; ++j) c[j] = coef[j];

    const int b  = blockIdx.x >> 6;
    const int ch = blockIdx.x & 63;
    const int ks = ch >> 5;
    const int jf = ch & 7;
    const int lhi = ((ch & 31) >> 3) << 4;

    #pragma unroll
    for (int r = 0; r < 2; ++r) {
        const int n = tid + r * 256;
        const float t = qp[n] * 0.125f;  // 1/sqrt(64)
        float P = c[NJ - 1];
        float Q = c[2 * NJ - 1];
        #pragma unroll
        for (int j = NJ - 2; j >= 0; --j) {
            P = fmaf(P, t, c[j]);
            Q = fmaf(Q, t, c[NJ + j]);
        }
        const float val = P / Q;
        ushort hi, lo;
        split2(val, hi, lo);
        const int gseq = b * NN + n;
        const int stg  = gseq >> 4;
        const int lane = lhi | (gseq & 15);
        const size_t addr = ((size_t)(stg * 2 + ks) * 64 + lane) * 8 + jf;
        SAh[addr] = hi;
        SAl[addr] = lo;
    }
}

// -------------------------------------------------------------------------
// Kernel 3: out = SA(4096x64) @ Wo(64x512) on the MFMA pipe.
// (unchanged from R2: all 16 Wo-fragment b128 loads hoisted, 16-deep MLP)
// -------------------------------------------------------------------------
__global__ __launch_bounds__(256) void out_mfma(const ushort* __restrict__ SAh,
                                                const ushort* __restrict__ SAl,
                                                const ushort* __restrict__ Woh,
                                                const ushort* __restrict__ Wol,
                                                float* __restrict__ out) {
    const int widx = blockIdx.x * 4 + (threadIdx.x >> 6);  // 0..2047
    const int st   = widx >> 3;        // 0..255
    const int dg   = widx & 7;         // 64-d group
    const int lane = threadIdx.x & 63;
    const int lm   = lane & 15;
    const int quad = lane >> 4;

    // hoist all Wo fragments (independent of SA)
    s8v wh0[4], wh1[4], wl0[4], wl1[4];
    #pragma unroll
    for (int dti = 0; dti < 4; ++dti) {
        const int dt = dg * 4 + dti;
        const ushort* wo_h = Woh + ((size_t)(dt * 2) * 64 + lane) * 8;
        const ushort* wo_l = Wol + ((size_t)(dt * 2) * 64 + lane) * 8;
        wh0[dti] = *(const s8v*)(wo_h);
        wh1[dti] = *(const s8v*)(wo_h + 512);
        wl0[dti] = *(const s8v*)(wo_l);
        wl1[dti] = *(const s8v*)(wo_l + 512);
    }

    const ushort* sa_h = SAh + ((size_t)(st * 2) * 64 + lane) * 8;
    const ushort* sa_l = SAl + ((size_t)(st * 2) * 64 + lane) * 8;
    const s8v ah0 = *(const s8v*)(sa_h);
    const s8v ah1 = *(const s8v*)(sa_h + 512);
    const s8v al0 = *(const s8v*)(sa_l);
    const s8v al1 = *(const s8v*)(sa_l + 512);

    const int seq0 = st * 16 + quad * 4;

    #pragma unroll
    for (int dti = 0; dti < 4; ++dti) {
        const int dt = dg * 4 + dti;
        const int d  = dt * 16 + lm;

        f32x4 acc = {0.f, 0.f, 0.f, 0.f};
        acc = __builtin_amdgcn_mfma_f32_16x16x32_bf16(ah0, wh0[dti], acc, 0, 0, 0);
        acc = __builtin_amdgcn_mfma_f32_16x16x32_bf16(ah0, wl0[dti], acc, 0, 0, 0);
        acc = __builtin_amdgcn_mfma_f32_16x16x32_bf16(al0, wh0[dti], acc, 0, 0, 0);
        acc = __builtin_amdgcn_mfma_f32_16x16x32_bf16(ah1, wh1[dti], acc, 0, 0, 0);
        acc = __builtin_amdgcn_mfma_f32_16x16x32_bf16(ah1, wl1[dti], acc, 0, 0, 0);
        acc = __builtin_amdgcn_mfma_f32_16x16x32_bf16(al1, wh1[dti], acc, 0, 0, 0);

        #pragma unroll
        for (int r = 0; r < 4; ++r)
            out[(size_t)(seq0 + r) * DD + d] = acc[r];
    }
}

extern "C" void kernel_launch(void* const* d_in, const int* in_sizes, int n_in,
                              void* d_out, int out_size, void* d_ws, size_t ws_size,
                              hipStream_t stream) {
    const float* X    = (const float*)d_in[0];  // (8,512,512)
    const float* Wqkv = (const float*)d_in[1];  // (512,192)
    const float* Wo   = (const float*)d_in[2];  // (64,512)
    float* out = (float*)d_out;                 // (8,512,512)

    float*  qkv = (float*)d_ws;                         // 3 MB
    ushort* SAh = (ushort*)(qkv + (size_t)3 * CHN);     // 512 KB
    ushort* SAl = SAh + (size_t)SAEL;                   // 512 KB
    ushort* Woh = SAl + (size_t)SAEL;                   // 64 KB
    ushort* Wol = Woh + (size_t)WOEL;                   // 64 KB

    qkv_fused<<<dim3(256), 768, 0, stream>>>(X, Wqkv, qkv);
    attn_taylor<<<dim3(BB * DKK), 256, 0, stream>>>(qkv, Wo, Woh, Wol, SAh, SAl);
    out_mfma<<<dim3(512), 256, 0, stream>>>(SAh, SAl, Woh, Wol, out);
}